// Round 3
// baseline (560.423 us; speedup 1.0000x reference)
//
#include <hip/hip_runtime.h>
#include <hip/hip_bf16.h>

// PoolAggregator: out[b,h] = mean_s relu( W @ features[idx[b,s]] + bias )
// B=10000, S=32, N=100000, D_IN=512, D_H=512.
//
// Phase 1: H[n,:] = relu(W @ features[n] + b) for ALL nodes -> bf16 in d_ws.
//   - XCD-chunked tile swizzle: the 4 n-tiles of one m-tile run back-to-back on
//     the same XCD -> feat rows fetched from HBM once (L2 reuse), not 4x.
//   - Epilogue staged through LDS -> coalesced 16B bf16 stores (no partial-line RMW).
//   - A(feat)-tile register prefetch (T14) to hide HBM latency under MFMA.
// Phase 2: out[b,:] = mean_s H[idx[b,s],:]  (gather + mean, H is L2/L3-resident).

#define S_NB 32
#define D_IN 512
#define D_H  512
#define BM   128
#define BN   128
#define BK   64
#define NNODE 100000
#define NBATCH 10000
#define NTILE_N (D_H / BN)                       // 4
#define NTILE_M ((NNODE + BM - 1) / BM)          // 782
#define NTILES  (NTILE_N * NTILE_M)              // 3128 = 8 * 391

typedef __attribute__((ext_vector_type(8))) short  short8;   // 8 bf16 = 4 VGPR
typedef __attribute__((ext_vector_type(4))) float  f32x4;
typedef __attribute__((ext_vector_type(4))) unsigned short us4;
typedef __attribute__((ext_vector_type(8))) unsigned short us8;

__device__ __forceinline__ unsigned short f2bf(float x) {
  union { float f; unsigned u; } v; v.f = x;
  unsigned r = v.u + 0x7FFFu + ((v.u >> 16) & 1u);
  return (unsigned short)(r >> 16);
}

__device__ __forceinline__ float bf2f(unsigned short x) {
  union { unsigned u; float f; } v; v.u = ((unsigned)x) << 16;
  return v.f;
}

// byte offset into a [128][64]-bf16 tile (row stride 128B) with XOR swizzle (T2)
__device__ __forceinline__ int swz(int row, int cb) {
  return row * 128 + (cb ^ ((row & 7) << 4));
}

// ---------------- Phase 1: H = relu(feat @ W^T + b) -> bf16 ----------------
__global__ __launch_bounds__(256, 4)
void gemm_h(const float* __restrict__ feat,
            const float* __restrict__ Wm,
            const float* __restrict__ bias,
            unsigned short* __restrict__ Hb) {
  const int tid  = threadIdx.x;
  const int lane = tid & 63;
  const int wid  = tid >> 6;
  const int wr   = wid >> 1;
  const int wc   = wid & 1;

  // XCD-chunked swizzle: 3128 = 8 XCDs x 391 tiles; n-tile fastest.
  const int bid  = blockIdx.x;
  const int tile = (bid & 7) * (NTILES / 8) + (bid >> 3);
  const int n0   = (tile & (NTILE_N - 1)) * BN;
  const int m0   = (tile / NTILE_N) * BM;

  __shared__ __align__(16) unsigned short smem[BM * BK * 2];  // 32 KB
  unsigned short* As = smem;
  unsigned short* Bs = smem + BM * BK;

  const int lr = tid >> 4;
  const int lc = tid & 15;

  const float* aptr[8];
  const float* wptr[8];
#pragma unroll
  for (int p = 0; p < 8; ++p) {
    int row = p * 16 + lr;
    int gr  = m0 + row; if (gr > NNODE - 1) gr = NNODE - 1;   // clamp pad rows
    aptr[p] = feat + (size_t)gr * D_IN + lc * 4;
    wptr[p] = Wm + (size_t)(n0 + row) * D_IN + lc * 4;
  }

  f32x4 acc[4][4];
#pragma unroll
  for (int i = 0; i < 4; ++i)
#pragma unroll
    for (int j = 0; j < 4; ++j)
      acc[i][j] = (f32x4){0.f, 0.f, 0.f, 0.f};

  const int frow = lane & 15;
  const int kcb  = (lane >> 4) * 16;
  const int arow = wr * 64 + frow;
  const int brow = wc * 64 + frow;

  // prologue: K-tile 0 of A in regs
  f32x4 aC[8];
#pragma unroll
  for (int p = 0; p < 8; ++p) aC[p] = *(const f32x4*)(aptr[p]);

#pragma unroll
  for (int ki = 0; ki < D_IN / BK; ++ki) {
    const int k0 = ki * BK;

    // T14: issue next A-tile loads early (complete during this tile's MFMA)
    f32x4 aN[8];
    if (ki < D_IN / BK - 1) {
#pragma unroll
      for (int p = 0; p < 8; ++p) aN[p] = *(const f32x4*)(aptr[p] + k0 + BK);
    }

    __syncthreads();   // previous iteration's LDS readers done
#pragma unroll
    for (int p = 0; p < 8; ++p) {
      int row = p * 16 + lr;
      f32x4 wv = *(const f32x4*)(wptr[p] + k0);   // W: L2-hot
      us4 a4, w4;
      a4.x = f2bf(aC[p].x); a4.y = f2bf(aC[p].y); a4.z = f2bf(aC[p].z); a4.w = f2bf(aC[p].w);
      w4.x = f2bf(wv.x);    w4.y = f2bf(wv.y);    w4.z = f2bf(wv.z);    w4.w = f2bf(wv.w);
      *(us4*)((char*)As + swz(row, lc * 8)) = a4;
      *(us4*)((char*)Bs + swz(row, lc * 8)) = w4;
    }
    __syncthreads();

#pragma unroll
    for (int kk = 0; kk < 2; ++kk) {
      short8 af[4], bfr[4];
#pragma unroll
      for (int mi = 0; mi < 4; ++mi)
        af[mi] = *(const short8*)((const char*)As + swz(arow + mi * 16, kk * 64 + kcb));
#pragma unroll
      for (int ni = 0; ni < 4; ++ni)
        bfr[ni] = *(const short8*)((const char*)Bs + swz(brow + ni * 16, kk * 64 + kcb));
#pragma unroll
      for (int mi = 0; mi < 4; ++mi)
#pragma unroll
        for (int ni = 0; ni < 4; ++ni)
          acc[mi][ni] = __builtin_amdgcn_mfma_f32_16x16x32_bf16(af[mi], bfr[ni], acc[mi][ni], 0, 0, 0);
    }

    if (ki < D_IN / BK - 1) {
#pragma unroll
      for (int p = 0; p < 8; ++p) aC[p] = aN[p];
    }
  }

  // ---- Epilogue: bias+ReLU -> bf16 into LDS C-tile, then coalesced stores ----
  __syncthreads();   // all LDS reads of As/Bs complete before overwrite
  unsigned short* Cs = smem;   // [128][128] ushort = 32 KB, exact overlay
  const int rq = lane >> 4;
#pragma unroll
  for (int ni = 0; ni < 4; ++ni) {
    int col = wc * 64 + ni * 16 + frow;
    float bv = bias[n0 + col];
#pragma unroll
    for (int mi = 0; mi < 4; ++mi) {
#pragma unroll
      for (int r = 0; r < 4; ++r) {
        int row = wr * 64 + mi * 16 + rq * 4 + r;
        Cs[row * 128 + col] = f2bf(fmaxf(acc[mi][ni][r] + bv, 0.f));
      }
    }
  }
  __syncthreads();

  // 256 threads store 16 rows/iter x 8 iters; 16B per thread per row
  const int srow = tid >> 4;          // 0..15
  const int scol = (tid & 15) * 8;    // ushort offset within 128-col row
#pragma unroll
  for (int it = 0; it < 8; ++it) {
    int row  = it * 16 + srow;
    int grow = m0 + row;
    us8 v = *(const us8*)(Cs + row * 128 + scol);
    if (grow < NNODE)
      *(us8*)(Hb + (size_t)grow * D_H + n0 + scol) = v;
  }
}

// ---------------- Phase 2: out[b,:] = mean_s H[idx[b,s],:] ----------------
__global__ __launch_bounds__(256, 8)
void pool_mean(const unsigned short* __restrict__ Hb,
               const int* __restrict__ nidx,
               float* __restrict__ out) {
  const int b2   = blockIdx.x;           // pair of nodes
  const int half = threadIdx.x >> 7;     // 0/1 -> which node
  const int t    = threadIdx.x & 127;
  const int b    = b2 * 2 + half;

  __shared__ int rows[2][S_NB];
  if (threadIdx.x < 2 * S_NB)
    rows[threadIdx.x >> 5][threadIdx.x & 31] = nidx[b2 * 2 * S_NB + threadIdx.x];
  __syncthreads();

  const int c = t * 4;                   // 4 cols per thread (8B loads)
  float s0 = 0.f, s1 = 0.f, s2 = 0.f, s3 = 0.f;
#pragma unroll
  for (int s = 0; s < S_NB; ++s) {
    us4 v = *(const us4*)(Hb + (size_t)rows[half][s] * D_H + c);
    s0 += bf2f(v.x); s1 += bf2f(v.y); s2 += bf2f(v.z); s3 += bf2f(v.w);
  }
  f32x4 o; o.x = s0 * (1.0f / S_NB); o.y = s1 * (1.0f / S_NB);
  o.z = s2 * (1.0f / S_NB); o.w = s3 * (1.0f / S_NB);
  *(f32x4*)(out + (size_t)b * D_H + c) = o;
}

// ---------------- Fallback: fused gathered GEMM (round-1 kernel) ----------------
__global__ __launch_bounds__(256, 4)
void pool_aggr_gemm(const int* __restrict__ nidx_g,
                    const float* __restrict__ feat,
                    const float* __restrict__ Wm,
                    const float* __restrict__ bias,
                    float* __restrict__ out) {
  const int tid  = threadIdx.x;
  const int lane = tid & 63;
  const int wid  = tid >> 6;
  const int wr   = wid >> 1;
  const int wc   = wid & 1;
  const int n0   = blockIdx.x * BN;
  const int mb   = blockIdx.y;

  __shared__ __align__(16) unsigned short As[BM * BK];
  __shared__ __align__(16) unsigned short Bs[BM * BK];
  __shared__ int nid[BM];

  if (tid < BM) nid[tid] = nidx_g[mb * BM + tid];
  __syncthreads();

  const int lr = tid >> 4;
  const int lc = tid & 15;

  const float* aptr[8];
  const float* wptr[8];
#pragma unroll
  for (int p = 0; p < 8; ++p) {
    int row = p * 16 + lr;
    aptr[p] = feat + (size_t)nid[row] * D_IN + lc * 4;
    wptr[p] = Wm + (size_t)(n0 + row) * D_IN + lc * 4;
  }

  f32x4 acc[4][4];
#pragma unroll
  for (int i = 0; i < 4; ++i)
#pragma unroll
    for (int j = 0; j < 4; ++j)
      acc[i][j] = (f32x4){0.f, 0.f, 0.f, 0.f};

  const int frow = lane & 15;
  const int kcb  = (lane >> 4) * 16;
  const int arow = wr * 64 + frow;
  const int brow = wc * 64 + frow;

  for (int k0 = 0; k0 < D_IN; k0 += BK) {
    __syncthreads();
#pragma unroll
    for (int p = 0; p < 8; ++p) {
      int row = p * 16 + lr;
      f32x4 av = *(const f32x4*)(aptr[p] + k0);
      f32x4 wv = *(const f32x4*)(wptr[p] + k0);
      us4 a4, w4;
      a4.x = f2bf(av.x); a4.y = f2bf(av.y); a4.z = f2bf(av.z); a4.w = f2bf(av.w);
      w4.x = f2bf(wv.x); w4.y = f2bf(wv.y); w4.z = f2bf(wv.z); w4.w = f2bf(wv.w);
      *(us4*)((char*)As + swz(row, lc * 8)) = a4;
      *(us4*)((char*)Bs + swz(row, lc * 8)) = w4;
    }
    __syncthreads();

#pragma unroll
    for (int kk = 0; kk < 2; ++kk) {
      short8 af[4], bfr[4];
#pragma unroll
      for (int mi = 0; mi < 4; ++mi)
        af[mi] = *(const short8*)((const char*)As + swz(arow + mi * 16, kk * 64 + kcb));
#pragma unroll
      for (int ni = 0; ni < 4; ++ni)
        bfr[ni] = *(const short8*)((const char*)Bs + swz(brow + ni * 16, kk * 64 + kcb));
#pragma unroll
      for (int mi = 0; mi < 4; ++mi)
#pragma unroll
        for (int ni = 0; ni < 4; ++ni)
          acc[mi][ni] = __builtin_amdgcn_mfma_f32_16x16x32_bf16(af[mi], bfr[ni], acc[mi][ni], 0, 0, 0);
    }
  }

  const int rq = lane >> 4;
#pragma unroll
  for (int ni = 0; ni < 4; ++ni) {
    int col = n0 + wc * 64 + ni * 16 + frow;
    float bv = bias[col];
#pragma unroll
    for (int bl = 0; bl < 2; ++bl) {
      float s = 0.f;
#pragma unroll
      for (int m2 = 0; m2 < 2; ++m2) {
        int mi = bl * 2 + m2;
#pragma unroll
        for (int r = 0; r < 4; ++r)
          s += fmaxf(acc[mi][ni][r] + bv, 0.f);
      }
      s += __shfl_xor(s, 16);
      s += __shfl_xor(s, 32);
      if (rq == 0) {
        int bb = mb * 4 + wr * 2 + bl;
        out[(size_t)bb * D_H + col] = s * (1.0f / (float)S_NB);
      }
    }
  }
}

extern "C" void kernel_launch(void* const* d_in, const int* in_sizes, int n_in,
                              void* d_out, int out_size, void* d_ws, size_t ws_size,
                              hipStream_t stream) {
  const int*   nidx = (const int*)d_in[0];    // [10000,32]
  const float* feat = (const float*)d_in[1];  // [100000,512]
  const float* Wm   = (const float*)d_in[2];  // [512,512]
  const float* bias = (const float*)d_in[3];  // [512]
  float* out = (float*)d_out;                 // [10000,512]

  const size_t h_bytes = (size_t)NNODE * D_H * sizeof(unsigned short);  // 102.4 MB

  if (ws_size >= h_bytes) {
    unsigned short* Hb = (unsigned short*)d_ws;
    gemm_h<<<NTILES, 256, 0, stream>>>(feat, Wm, bias, Hb);
    pool_mean<<<NBATCH / 2, 256, 0, stream>>>(Hb, nidx, out);
  } else {
    dim3 grid(D_H / BN, NBATCH / 4);
    pool_aggr_gemm<<<grid, 256, 0, stream>>>(nidx, feat, Wm, bias, out);
  }
}

// Round 4
// 197.095 us; speedup vs baseline: 2.8434x; 2.8434x over previous
//
#include <hip/hip_runtime.h>
#include <hip/hip_bf16.h>

// PoolAggregator: out[b,h] = mean_s relu( W @ features[idx[b,s]] + bias )
// B=10000, S=32, N=100000, D_IN=512, D_H=512.
//
// Pipeline (ws >= 205.3 MB):
//   0) cvt_bf16: feat f32 -> featb bf16 (102.4 MB), W f32 -> Wb bf16 (0.5 MB)
//   1) gemm_hb:  H = relu(featb @ Wb^T + b) -> bf16, m97-style global_load_lds
//      staging (async, width=16) with pre-swizzled global source matching the
//      XOR LDS read swizzle; XCD-chunked tile order (392 tiles/XCD, %4==0);
//      LDS-staged coalesced epilogue stores.
//   2) pool_mean: out[b,:] = mean_s H[idx[b,s],:]
// Fallbacks: ws >= 102.4 MB -> round-2 f32-reg-staged gemm (measured 414us);
//            else fused gathered GEMM.

#define S_NB 32
#define D_IN 512
#define D_H  512
#define BM   128
#define BN   128
#define BK   64
#define NNODE 100000
#define NBATCH 10000
#define NTILE_N (D_H / BN)          // 4
#define NTILE_M 784                 // ceil(100000/128)=782, padded to 784 for XCD chunks
#define NTILES  (NTILE_N * NTILE_M) // 3136 = 8 * 392, 392 % 4 == 0

typedef __attribute__((ext_vector_type(8))) short  short8;
typedef __attribute__((ext_vector_type(4))) float  f32x4;
typedef __attribute__((ext_vector_type(4))) unsigned short us4;
typedef __attribute__((ext_vector_type(8))) unsigned short us8;

__device__ __forceinline__ unsigned short f2bf(float x) {
  union { float f; unsigned u; } v; v.f = x;
  unsigned r = v.u + 0x7FFFu + ((v.u >> 16) & 1u);
  return (unsigned short)(r >> 16);
}

__device__ __forceinline__ float bf2f(unsigned short x) {
  union { unsigned u; float f; } v; v.u = ((unsigned)x) << 16;
  return v.f;
}

// byte offset into a [128][64]-bf16 LDS tile (row stride 128B) with XOR swizzle
__device__ __forceinline__ int swz(int row, int cb) {
  return row * 128 + (cb ^ ((row & 7) << 4));
}

// async global->LDS, 16B per lane; lptr is wave-uniform base, gptr per-lane
__device__ __forceinline__ void gld_lds16(const unsigned short* g, unsigned short* l) {
  __builtin_amdgcn_global_load_lds(
      (const __attribute__((address_space(1))) unsigned int*)g,
      (__attribute__((address_space(3))) unsigned int*)l, 16, 0, 0);
}

// ---------------- Phase 0: f32 -> bf16 conversion (vectorized, grid-stride) ----------------
__global__ __launch_bounds__(256, 8)
void cvt_bf16(const float* __restrict__ src, unsigned short* __restrict__ dst, int n8) {
  int i = blockIdx.x * blockDim.x + threadIdx.x;
  const int stride = gridDim.x * blockDim.x;
  for (; i < n8; i += stride) {
    f32x4 a = *(const f32x4*)(src + (size_t)i * 8);
    f32x4 b = *(const f32x4*)(src + (size_t)i * 8 + 4);
    us8 o;
    o[0] = f2bf(a.x); o[1] = f2bf(a.y); o[2] = f2bf(a.z); o[3] = f2bf(a.w);
    o[4] = f2bf(b.x); o[5] = f2bf(b.y); o[6] = f2bf(b.z); o[7] = f2bf(b.w);
    *(us8*)(dst + (size_t)i * 8) = o;
  }
}

// ---------------- Phase 1: H = relu(featb @ Wb^T + b) -> bf16 ----------------
__global__ __launch_bounds__(256, 4)
void gemm_hb(const unsigned short* __restrict__ featb,
             const unsigned short* __restrict__ Wb,
             const float* __restrict__ bias,
             unsigned short* __restrict__ Hb) {
  const int tid  = threadIdx.x;
  const int lane = tid & 63;
  const int wid  = tid >> 6;
  const int wr   = wid >> 1;
  const int wc   = wid & 1;

  // XCD-chunked swizzle: XCD k (bid%8) gets 392 sequential tiles, n-tile fastest.
  const int bid  = blockIdx.x;
  const int tile = (bid & 7) * (NTILES / 8) + (bid >> 3);
  const int n0   = (tile & 3) * BN;
  const int m0   = (tile >> 2) * BM;

  __shared__ __align__(16) unsigned short smem[BM * BK * 2];  // 32 KB
  unsigned short* As = smem;
  unsigned short* Bs = smem + BM * BK;

  // ---- staging geometry: wave w covers rows [32w, 32w+32), 4 insts per tile ----
  // inst i, lane l -> row_local = 32w + 8i + (l>>3), LDS granule g' = l&7;
  // source granule g = g' ^ (row_local&7) so that physical LDS layout == swz().
  const unsigned short* srcA[4];
  const unsigned short* srcB[4];
  unsigned short* dstA[4];
  unsigned short* dstB[4];
#pragma unroll
  for (int i = 0; i < 4; ++i) {
    int rl = wid * 32 + i * 8 + (lane >> 3);
    int g  = (lane & 7) ^ (rl & 7);
    int ra = m0 + rl; if (ra > NNODE - 1) ra = NNODE - 1;   // clamp pad rows
    srcA[i] = featb + (size_t)ra * D_IN + g * 8;
    srcB[i] = Wb + (size_t)(n0 + rl) * D_IN + g * 8;
    dstA[i] = As + (wid * 32 + i * 8) * 64;
    dstB[i] = Bs + (wid * 32 + i * 8) * 64;
  }

  f32x4 acc[4][4];
#pragma unroll
  for (int i = 0; i < 4; ++i)
#pragma unroll
    for (int j = 0; j < 4; ++j)
      acc[i][j] = (f32x4){0.f, 0.f, 0.f, 0.f};

  const int frow = lane & 15;
  const int kcb  = (lane >> 4) * 16;
  const int arow = wr * 64 + frow;
  const int brow = wc * 64 + frow;

  for (int ki = 0; ki < D_IN / BK; ++ki) {
    const int k0 = ki * BK;
    if (ki) __syncthreads();            // WAR: previous tile's readers done
#pragma unroll
    for (int i = 0; i < 4; ++i) {
      gld_lds16(srcA[i] + k0, dstA[i]);
      gld_lds16(srcB[i] + k0, dstB[i]);
    }
    __syncthreads();                    // RAW: staged data visible (drains vmcnt)

#pragma unroll
    for (int kk = 0; kk < 2; ++kk) {
      short8 af[4], bfr[4];
#pragma unroll
      for (int mi = 0; mi < 4; ++mi)
        af[mi] = *(const short8*)((const char*)As + swz(arow + mi * 16, kk * 64 + kcb));
#pragma unroll
      for (int ni = 0; ni < 4; ++ni)
        bfr[ni] = *(const short8*)((const char*)Bs + swz(brow + ni * 16, kk * 64 + kcb));
#pragma unroll
      for (int mi = 0; mi < 4; ++mi)
#pragma unroll
        for (int ni = 0; ni < 4; ++ni)
          acc[mi][ni] = __builtin_amdgcn_mfma_f32_16x16x32_bf16(af[mi], bfr[ni], acc[mi][ni], 0, 0, 0);
    }
  }

  // ---- Epilogue: bias+ReLU -> bf16 via LDS, then coalesced 16B stores ----
  __syncthreads();                      // all LDS reads done before overlay
  unsigned short* Cs = smem;            // [128][128] ushort = 32 KB overlay
  const int rq = lane >> 4;
#pragma unroll
  for (int ni = 0; ni < 4; ++ni) {
    int col = wc * 64 + ni * 16 + frow;
    float bv = bias[n0 + col];
#pragma unroll
    for (int mi = 0; mi < 4; ++mi) {
#pragma unroll
      for (int r = 0; r < 4; ++r) {
        int row = wr * 64 + mi * 16 + rq * 4 + r;
        Cs[row * 128 + col] = f2bf(fmaxf(acc[mi][ni][r] + bv, 0.f));
      }
    }
  }
  __syncthreads();

  const int srow = tid >> 4;
  const int scol = (tid & 15) * 8;
#pragma unroll
  for (int it = 0; it < 8; ++it) {
    int row  = it * 16 + srow;
    int grow = m0 + row;
    us8 v = *(const us8*)(Cs + row * 128 + scol);
    if (grow < NNODE)
      *(us8*)(Hb + (size_t)grow * D_H + n0 + scol) = v;
  }
}

// ---------------- Phase 2: out[b,:] = mean_s H[idx[b,s],:] ----------------
__global__ __launch_bounds__(256, 8)
void pool_mean(const unsigned short* __restrict__ Hb,
               const int* __restrict__ nidx,
               float* __restrict__ out) {
  const int b2   = blockIdx.x;
  const int half = threadIdx.x >> 7;
  const int t    = threadIdx.x & 127;
  const int b    = b2 * 2 + half;

  __shared__ int rows[2][S_NB];
  if (threadIdx.x < 2 * S_NB)
    rows[threadIdx.x >> 5][threadIdx.x & 31] = nidx[b2 * 2 * S_NB + threadIdx.x];
  __syncthreads();

  const int c = t * 4;
  float s0 = 0.f, s1 = 0.f, s2 = 0.f, s3 = 0.f;
#pragma unroll
  for (int s = 0; s < S_NB; ++s) {
    us4 v = *(const us4*)(Hb + (size_t)rows[half][s] * D_H + c);
    s0 += bf2f(v.x); s1 += bf2f(v.y); s2 += bf2f(v.z); s3 += bf2f(v.w);
  }
  f32x4 o; o.x = s0 * (1.0f / S_NB); o.y = s1 * (1.0f / S_NB);
  o.z = s2 * (1.0f / S_NB); o.w = s3 * (1.0f / S_NB);
  *(f32x4*)(out + (size_t)b * D_H + c) = o;
}

// ---------------- Fallback A: round-2 f32 reg-staged GEMM (measured 414us) ----------------
__global__ __launch_bounds__(256, 4)
void gemm_h(const float* __restrict__ feat,
            const float* __restrict__ Wm,
            const float* __restrict__ bias,
            unsigned short* __restrict__ Hb) {
  const int tid  = threadIdx.x;
  const int lane = tid & 63;
  const int wid  = tid >> 6;
  const int wr   = wid >> 1;
  const int wc   = wid & 1;
  const int n0   = blockIdx.x * BN;
  const int m0   = blockIdx.y * BM;

  __shared__ __align__(16) unsigned short As[BM * BK];
  __shared__ __align__(16) unsigned short Bs[BM * BK];

  const int lr = tid >> 4;
  const int lc = tid & 15;

  const float* aptr[8];
  const float* wptr[8];
#pragma unroll
  for (int p = 0; p < 8; ++p) {
    int row = p * 16 + lr;
    int gr  = m0 + row; if (gr > NNODE - 1) gr = NNODE - 1;
    aptr[p] = feat + (size_t)gr * D_IN + lc * 4;
    wptr[p] = Wm + (size_t)(n0 + row) * D_IN + lc * 4;
  }

  f32x4 acc[4][4];
#pragma unroll
  for (int i = 0; i < 4; ++i)
#pragma unroll
    for (int j = 0; j < 4; ++j)
      acc[i][j] = (f32x4){0.f, 0.f, 0.f, 0.f};

  const int frow = lane & 15;
  const int kcb  = (lane >> 4) * 16;
  const int arow = wr * 64 + frow;
  const int brow = wc * 64 + frow;

  for (int k0 = 0; k0 < D_IN; k0 += BK) {
    __syncthreads();
#pragma unroll
    for (int p = 0; p < 8; ++p) {
      int row = p * 16 + lr;
      f32x4 av = *(const f32x4*)(aptr[p] + k0);
      f32x4 wv = *(const f32x4*)(wptr[p] + k0);
      us4 a4, w4;
      a4.x = f2bf(av.x); a4.y = f2bf(av.y); a4.z = f2bf(av.z); a4.w = f2bf(av.w);
      w4.x = f2bf(wv.x); w4.y = f2bf(wv.y); w4.z = f2bf(wv.z); w4.w = f2bf(wv.w);
      *(us4*)((char*)As + swz(row, lc * 8)) = a4;
      *(us4*)((char*)Bs + swz(row, lc * 8)) = w4;
    }
    __syncthreads();

#pragma unroll
    for (int kk = 0; kk < 2; ++kk) {
      short8 af[4], bfr[4];
#pragma unroll
      for (int mi = 0; mi < 4; ++mi)
        af[mi] = *(const short8*)((const char*)As + swz(arow + mi * 16, kk * 64 + kcb));
#pragma unroll
      for (int ni = 0; ni < 4; ++ni)
        bfr[ni] = *(const short8*)((const char*)Bs + swz(brow + ni * 16, kk * 64 + kcb));
#pragma unroll
      for (int mi = 0; mi < 4; ++mi)
#pragma unroll
        for (int ni = 0; ni < 4; ++ni)
          acc[mi][ni] = __builtin_amdgcn_mfma_f32_16x16x32_bf16(af[mi], bfr[ni], acc[mi][ni], 0, 0, 0);
    }
  }

  const int rq = lane >> 4;
#pragma unroll
  for (int ni = 0; ni < 4; ++ni) {
    int col = n0 + wc * 64 + ni * 16 + frow;
    float bv = bias[col];
#pragma unroll
    for (int mi = 0; mi < 4; ++mi) {
#pragma unroll
      for (int r = 0; r < 4; ++r) {
        int grow = m0 + wr * 64 + mi * 16 + rq * 4 + r;
        if (grow < NNODE)
          Hb[(size_t)grow * D_H + col] = f2bf(fmaxf(acc[mi][ni][r] + bv, 0.f));
      }
    }
  }
}

// ---------------- Fallback B: fused gathered GEMM (round-1) ----------------
__global__ __launch_bounds__(256, 4)
void pool_aggr_gemm(const int* __restrict__ nidx_g,
                    const float* __restrict__ feat,
                    const float* __restrict__ Wm,
                    const float* __restrict__ bias,
                    float* __restrict__ out) {
  const int tid  = threadIdx.x;
  const int lane = tid & 63;
  const int wid  = tid >> 6;
  const int wr   = wid >> 1;
  const int wc   = wid & 1;
  const int n0   = blockIdx.x * BN;
  const int mb   = blockIdx.y;

  __shared__ __align__(16) unsigned short As[BM * BK];
  __shared__ __align__(16) unsigned short Bs[BM * BK];
  __shared__ int nid[BM];

  if (tid < BM) nid[tid] = nidx_g[mb * BM + tid];
  __syncthreads();

  const int lr = tid >> 4;
  const int lc = tid & 15;

  const float* aptr[8];
  const float* wptr[8];
#pragma unroll
  for (int p = 0; p < 8; ++p) {
    int row = p * 16 + lr;
    aptr[p] = feat + (size_t)nid[row] * D_IN + lc * 4;
    wptr[p] = Wm + (size_t)(n0 + row) * D_IN + lc * 4;
  }

  f32x4 acc[4][4];
#pragma unroll
  for (int i = 0; i < 4; ++i)
#pragma unroll
    for (int j = 0; j < 4; ++j)
      acc[i][j] = (f32x4){0.f, 0.f, 0.f, 0.f};

  const int frow = lane & 15;
  const int kcb  = (lane >> 4) * 16;
  const int arow = wr * 64 + frow;
  const int brow = wc * 64 + frow;

  for (int k0 = 0; k0 < D_IN; k0 += BK) {
    __syncthreads();
#pragma unroll
    for (int p = 0; p < 8; ++p) {
      int row = p * 16 + lr;
      f32x4 av = *(const f32x4*)(aptr[p] + k0);
      f32x4 wv = *(const f32x4*)(wptr[p] + k0);
      us4 a4, w4;
      a4.x = f2bf(av.x); a4.y = f2bf(av.y); a4.z = f2bf(av.z); a4.w = f2bf(av.w);
      w4.x = f2bf(wv.x); w4.y = f2bf(wv.y); w4.z = f2bf(wv.z); w4.w = f2bf(wv.w);
      *(us4*)((char*)As + swz(row, lc * 8)) = a4;
      *(us4*)((char*)Bs + swz(row, lc * 8)) = w4;
    }
    __syncthreads();

#pragma unroll
    for (int kk = 0; kk < 2; ++kk) {
      short8 af[4], bfr[4];
#pragma unroll
      for (int mi = 0; mi < 4; ++mi)
        af[mi] = *(const short8*)((const char*)As + swz(arow + mi * 16, kk * 64 + kcb));
#pragma unroll
      for (int ni = 0; ni < 4; ++ni)
        bfr[ni] = *(const short8*)((const char*)Bs + swz(brow + ni * 16, kk * 64 + kcb));
#pragma unroll
      for (int mi = 0; mi < 4; ++mi)
#pragma unroll
        for (int ni = 0; ni < 4; ++ni)
          acc[mi][ni] = __builtin_amdgcn_mfma_f32_16x16x32_bf16(af[mi], bfr[ni], acc[mi][ni], 0, 0, 0);
    }
  }

  const int rq = lane >> 4;
#pragma unroll
  for (int ni = 0; ni < 4; ++ni) {
    int col = n0 + wc * 64 + ni * 16 + frow;
    float bv = bias[col];
#pragma unroll
    for (int bl = 0; bl < 2; ++bl) {
      float s = 0.f;
#pragma unroll
      for (int m2 = 0; m2 < 2; ++m2) {
        int mi = bl * 2 + m2;
#pragma unroll
        for (int r = 0; r < 4; ++r)
          s += fmaxf(acc[mi][ni][r] + bv, 0.f);
      }
      s += __shfl_xor(s, 16);
      s += __shfl_xor(s, 32);
      if (rq == 0) {
        int bb = mb * 4 + wr * 2 + bl;
        out[(size_t)bb * D_H + col] = s * (1.0f / (float)S_NB);
      }
    }
  }
}

extern "C" void kernel_launch(void* const* d_in, const int* in_sizes, int n_in,
                              void* d_out, int out_size, void* d_ws, size_t ws_size,
                              hipStream_t stream) {
  const int*   nidx = (const int*)d_in[0];    // [10000,32]
  const float* feat = (const float*)d_in[1];  // [100000,512]
  const float* Wm   = (const float*)d_in[2];  // [512,512]
  const float* bias = (const float*)d_in[3];  // [512]
  float* out = (float*)d_out;                 // [10000,512]

  const size_t featb_bytes = (size_t)NNODE * D_IN * sizeof(unsigned short);  // 102.4 MB
  const size_t wb_bytes    = (size_t)D_H * D_IN * sizeof(unsigned short);    // 0.5 MB
  const size_t h_bytes     = (size_t)NNODE * D_H * sizeof(unsigned short);   // 102.4 MB

  if (ws_size >= featb_bytes + wb_bytes + h_bytes) {
    unsigned short* featb = (unsigned short*)d_ws;
    unsigned short* Wb    = featb + (size_t)NNODE * D_IN;
    unsigned short* Hb    = Wb + (size_t)D_H * D_IN;

    cvt_bf16<<<2048, 256, 0, stream>>>(feat, featb, NNODE * D_IN / 8);
    cvt_bf16<<<128, 256, 0, stream>>>(Wm, Wb, D_H * D_IN / 8);
    gemm_hb<<<NTILES, 256, 0, stream>>>(featb, Wb, bias, Hb);
    pool_mean<<<NBATCH / 2, 256, 0, stream>>>(Hb, nidx, out);
  } else if (ws_size >= h_bytes) {
    unsigned short* Hb = (unsigned short*)d_ws;
    dim3 g1(D_H / BN, (NNODE + BM - 1) / BM);
    gemm_h<<<g1, 256, 0, stream>>>(feat, Wm, bias, Hb);
    pool_mean<<<NBATCH / 2, 256, 0, stream>>>(Hb, nidx, out);
  } else {
    dim3 grid(D_H / BN, NBATCH / 4);
    pool_aggr_gemm<<<grid, 256, 0, stream>>>(nidx, feat, Wm, bias, out);
  }
}

// Round 5
// 192.246 us; speedup vs baseline: 2.9151x; 1.0252x over previous
//
#include <hip/hip_runtime.h>
#include <hip/hip_bf16.h>

// PoolAggregator: out[b,h] = mean_s relu( W @ features[idx[b,s]] + bias )
// B=10000, S=32, N=100000, D_IN=512, D_H=512.
//
// Pipeline (ws >= 103 MB):
//   0) cvt_bf16: W f32 -> Wb bf16 (0.5 MB) only.
//   1) gemm_hf: H = relu(feat @ Wb^T + b) -> bf16. Fused f32->bf16 for A:
//      double-buffered LDS (64 KB), T14 split (issue next A f32 loads + next W
//      global_load_lds BEFORE MFMA; cvt+ds_write AFTER), 1 barrier per K-step.
//      XCD-chunked tile order; coalesced LDS-staged epilogue stores.
//   2) pool_mean4: out[b,:] = mean_s H[idx[b,s],:] (4 nodes/block, 16B loads).
// Fallbacks: ws >= 102.4 MB -> round-2 f32-reg-staged gemm; else fused gather GEMM.

#define S_NB 32
#define D_IN 512
#define D_H  512
#define BM   128
#define BN   128
#define BK   64
#define NNODE 100000
#define NBATCH 10000
#define NTILE_N 4
#define NTILE_M 784                 // padded so NTILES = 8 * 392, 392 % 4 == 0
#define NTILES  (NTILE_N * NTILE_M) // 3136

typedef __attribute__((ext_vector_type(8))) short  short8;
typedef __attribute__((ext_vector_type(4))) float  f32x4;
typedef __attribute__((ext_vector_type(4))) unsigned short us4;
typedef __attribute__((ext_vector_type(8))) unsigned short us8;

__device__ __forceinline__ unsigned short f2bf(float x) {
  union { float f; unsigned u; } v; v.f = x;
  unsigned r = v.u + 0x7FFFu + ((v.u >> 16) & 1u);
  return (unsigned short)(r >> 16);
}

__device__ __forceinline__ float bf2f(unsigned short x) {
  union { unsigned u; float f; } v; v.u = ((unsigned)x) << 16;
  return v.f;
}

// byte offset into a [128][64]-bf16 LDS tile (row stride 128B) with XOR swizzle
__device__ __forceinline__ int swz(int row, int cb) {
  return row * 128 + (cb ^ ((row & 7) << 4));
}

// async global->LDS, 16B/lane; LDS dest wave-uniform base + lane*16
__device__ __forceinline__ void gld_lds16(const unsigned short* g, unsigned short* l) {
  __builtin_amdgcn_global_load_lds(
      (const __attribute__((address_space(1))) unsigned int*)g,
      (__attribute__((address_space(3))) unsigned int*)l, 16, 0, 0);
}

// ---------------- Phase 0: f32 -> bf16 (used for W only in primary path) ----------------
__global__ __launch_bounds__(256, 8)
void cvt_bf16(const float* __restrict__ src, unsigned short* __restrict__ dst, int n8) {
  int i = blockIdx.x * blockDim.x + threadIdx.x;
  const int stride = gridDim.x * blockDim.x;
  for (; i < n8; i += stride) {
    f32x4 a = *(const f32x4*)(src + (size_t)i * 8);
    f32x4 b = *(const f32x4*)(src + (size_t)i * 8 + 4);
    us8 o;
    o[0] = f2bf(a.x); o[1] = f2bf(a.y); o[2] = f2bf(a.z); o[3] = f2bf(a.w);
    o[4] = f2bf(b.x); o[5] = f2bf(b.y); o[6] = f2bf(b.z); o[7] = f2bf(b.w);
    *(us8*)(dst + (size_t)i * 8) = o;
  }
}

// ---------------- Phase 1: H = relu(feat @ Wb^T + b) -> bf16, fused cvt ----------------
__global__ __launch_bounds__(256, 2)
void gemm_hf(const float* __restrict__ feat,
             const unsigned short* __restrict__ Wb,
             const float* __restrict__ bias,
             unsigned short* __restrict__ Hb) {
  const int tid  = threadIdx.x;
  const int lane = tid & 63;
  const int wid  = tid >> 6;
  const int wr   = wid >> 1;
  const int wc   = wid & 1;

  // XCD-chunked swizzle: XCD k (bid%8) gets 392 sequential tiles, n-tile fastest.
  const int bid  = blockIdx.x;
  const int tile = (bid & 7) * (NTILES / 8) + (bid >> 3);
  const int n0   = (tile & 3) * BN;
  const int m0   = (tile >> 2) * BM;

  __shared__ __align__(16) unsigned short As[2][BM * BK];  // 32 KB
  __shared__ __align__(16) unsigned short Bs[2][BM * BK];  // 32 KB

  // A staging (f32 -> reg -> cvt -> swizzled LDS): thread covers
  // row = p*16 + tid/16, f32 cols [ (tid&15)*4, +4 )
  const int lr = tid >> 4;
  const int lc = tid & 15;
  const float* aptr[8];
  int awoff[8];
#pragma unroll
  for (int p = 0; p < 8; ++p) {
    int row = p * 16 + lr;
    int gr  = m0 + row; if (gr > NNODE - 1) gr = NNODE - 1;   // clamp pad rows
    aptr[p]  = feat + (size_t)gr * D_IN + lc * 4;
    awoff[p] = swz(row, lc * 8);
  }

  // W staging via global_load_lds with pre-swizzled source (LDS dest linear)
  const unsigned short* srcW[4];
  int wdoff[4];
#pragma unroll
  for (int i = 0; i < 4; ++i) {
    int rl = wid * 32 + i * 8 + (lane >> 3);
    int g  = (lane & 7) ^ (rl & 7);
    srcW[i]  = Wb + (size_t)(n0 + rl) * D_IN + g * 8;
    wdoff[i] = (wid * 32 + i * 8) * 64;
  }

  f32x4 acc[4][4];
#pragma unroll
  for (int i = 0; i < 4; ++i)
#pragma unroll
    for (int j = 0; j < 4; ++j)
      acc[i][j] = (f32x4){0.f, 0.f, 0.f, 0.f};

  const int frow = lane & 15;
  const int kcb  = (lane >> 4) * 16;
  const int arow = wr * 64 + frow;
  const int brow = wc * 64 + frow;

  // ---- prologue: stage K-tile 0 ----
  {
    f32x4 a0[8];
#pragma unroll
    for (int p = 0; p < 8; ++p) a0[p] = *(const f32x4*)(aptr[p]);
#pragma unroll
    for (int i = 0; i < 4; ++i) gld_lds16(srcW[i], &Bs[0][wdoff[i]]);
#pragma unroll
    for (int p = 0; p < 8; ++p) {
      us4 v;
      v.x = f2bf(a0[p].x); v.y = f2bf(a0[p].y); v.z = f2bf(a0[p].z); v.w = f2bf(a0[p].w);
      *(us4*)((char*)As[0] + awoff[p]) = v;
    }
  }
  __syncthreads();

  // ---- main loop: 1 barrier per K-step, double-buffered ----
#pragma unroll
  for (int ki = 0; ki < D_IN / BK; ++ki) {
    const int cur = ki & 1;

    // T14 issue-early: next A tile (regs) + next W tile (async LDS DMA)
    f32x4 an[8];
    if (ki < D_IN / BK - 1) {
#pragma unroll
      for (int p = 0; p < 8; ++p) an[p] = *(const f32x4*)(aptr[p] + (ki + 1) * BK);
#pragma unroll
      for (int i = 0; i < 4; ++i) gld_lds16(srcW[i] + (ki + 1) * BK, &Bs[cur ^ 1][wdoff[i]]);
    }

    // compute current buffer
#pragma unroll
    for (int kk = 0; kk < 2; ++kk) {
      short8 af[4], bfr[4];
#pragma unroll
      for (int mi = 0; mi < 4; ++mi)
        af[mi] = *(const short8*)((const char*)As[cur] + swz(arow + mi * 16, kk * 64 + kcb));
#pragma unroll
      for (int ni = 0; ni < 4; ++ni)
        bfr[ni] = *(const short8*)((const char*)Bs[cur] + swz(brow + ni * 16, kk * 64 + kcb));
#pragma unroll
      for (int mi = 0; mi < 4; ++mi)
#pragma unroll
        for (int ni = 0; ni < 4; ++ni)
          acc[mi][ni] = __builtin_amdgcn_mfma_f32_16x16x32_bf16(af[mi], bfr[ni], acc[mi][ni], 0, 0, 0);
    }

    // write-late: convert landed A into the other buffer
    if (ki < D_IN / BK - 1) {
#pragma unroll
      for (int p = 0; p < 8; ++p) {
        us4 v;
        v.x = f2bf(an[p].x); v.y = f2bf(an[p].y); v.z = f2bf(an[p].z); v.w = f2bf(an[p].w);
        *(us4*)((char*)As[cur ^ 1] + awoff[p]) = v;
      }
    }
    __syncthreads();   // buf[cur^1] complete (drains vmcnt+lgkmcnt); WAR on buf[cur] safe
  }

  // ---- Epilogue: bias+ReLU -> bf16 via LDS overlay, coalesced 16B stores ----
  unsigned short* Cs = &As[0][0];   // 128x128 ushort = 32 KB overlay (As fully reusable)
  const int rq = lane >> 4;
#pragma unroll
  for (int ni = 0; ni < 4; ++ni) {
    int col = wc * 64 + ni * 16 + frow;
    float bv = bias[n0 + col];
#pragma unroll
    for (int mi = 0; mi < 4; ++mi) {
#pragma unroll
      for (int r = 0; r < 4; ++r) {
        int row = wr * 64 + mi * 16 + rq * 4 + r;
        Cs[row * 128 + col] = f2bf(fmaxf(acc[mi][ni][r] + bv, 0.f));
      }
    }
  }
  __syncthreads();

  const int srow = tid >> 4;
  const int scol = (tid & 15) * 8;
#pragma unroll
  for (int it = 0; it < 8; ++it) {
    int row  = it * 16 + srow;
    int grow = m0 + row;
    us8 v = *(const us8*)(Cs + row * 128 + scol);
    if (grow < NNODE)
      *(us8*)(Hb + (size_t)grow * D_H + n0 + scol) = v;
  }
}

// ---------------- Phase 2: out[b,:] = mean_s H[idx[b,s],:] ----------------
__global__ __launch_bounds__(256, 8)
void pool_mean4(const unsigned short* __restrict__ Hb,
                const int* __restrict__ nidx,
                float* __restrict__ out) {
  const int b4 = blockIdx.x;            // group of 4 output nodes
  const int q  = threadIdx.x >> 6;      // which node in group
  const int t  = threadIdx.x & 63;
  const int b  = b4 * 4 + q;

  __shared__ int rows[4][S_NB];
  if (threadIdx.x < 4 * S_NB)
    rows[threadIdx.x >> 5][threadIdx.x & 31] = nidx[b4 * 4 * S_NB + threadIdx.x];
  __syncthreads();

  const int c = t * 8;                  // 8 cols per thread (16B loads)
  float s0 = 0.f, s1 = 0.f, s2 = 0.f, s3 = 0.f;
  float s4 = 0.f, s5 = 0.f, s6 = 0.f, s7 = 0.f;
#pragma unroll
  for (int s = 0; s < S_NB; ++s) {
    us8 v = *(const us8*)(Hb + (size_t)rows[q][s] * D_H + c);
    s0 += bf2f(v[0]); s1 += bf2f(v[1]); s2 += bf2f(v[2]); s3 += bf2f(v[3]);
    s4 += bf2f(v[4]); s5 += bf2f(v[5]); s6 += bf2f(v[6]); s7 += bf2f(v[7]);
  }
  const float inv = 1.0f / (float)S_NB;
  f32x4 o1; o1.x = s0 * inv; o1.y = s1 * inv; o1.z = s2 * inv; o1.w = s3 * inv;
  f32x4 o2; o2.x = s4 * inv; o2.y = s5 * inv; o2.z = s6 * inv; o2.w = s7 * inv;
  *(f32x4*)(out + (size_t)b * D_H + c)     = o1;
  *(f32x4*)(out + (size_t)b * D_H + c + 4) = o2;
}

// ---------------- Fallback A: round-2 f32 reg-staged GEMM ----------------
__global__ __launch_bounds__(256, 4)
void gemm_h(const float* __restrict__ feat,
            const float* __restrict__ Wm,
            const float* __restrict__ bias,
            unsigned short* __restrict__ Hb) {
  const int tid  = threadIdx.x;
  const int lane = tid & 63;
  const int wid  = tid >> 6;
  const int wr   = wid >> 1;
  const int wc   = wid & 1;
  const int n0   = blockIdx.x * BN;
  const int m0   = blockIdx.y * BM;

  __shared__ __align__(16) unsigned short As[BM * BK];
  __shared__ __align__(16) unsigned short Bs[BM * BK];

  const int lr = tid >> 4;
  const int lc = tid & 15;

  const float* aptr[8];
  const float* wptr[8];
#pragma unroll
  for (int p = 0; p < 8; ++p) {
    int row = p * 16 + lr;
    int gr  = m0 + row; if (gr > NNODE - 1) gr = NNODE - 1;
    aptr[p] = feat + (size_t)gr * D_IN + lc * 4;
    wptr[p] = Wm + (size_t)(n0 + row) * D_IN + lc * 4;
  }

  f32x4 acc[4][4];
#pragma unroll
  for (int i = 0; i < 4; ++i)
#pragma unroll
    for (int j = 0; j < 4; ++j)
      acc[i][j] = (f32x4){0.f, 0.f, 0.f, 0.f};

  const int frow = lane & 15;
  const int kcb  = (lane >> 4) * 16;
  const int arow = wr * 64 + frow;
  const int brow = wc * 64 + frow;

  for (int k0 = 0; k0 < D_IN; k0 += BK) {
    __syncthreads();
#pragma unroll
    for (int p = 0; p < 8; ++p) {
      int row = p * 16 + lr;
      f32x4 av = *(const f32x4*)(aptr[p] + k0);
      f32x4 wv = *(const f32x4*)(wptr[p] + k0);
      us4 a4, w4;
      a4.x = f2bf(av.x); a4.y = f2bf(av.y); a4.z = f2bf(av.z); a4.w = f2bf(av.w);
      w4.x = f2bf(wv.x); w4.y = f2bf(wv.y); w4.z = f2bf(wv.z); w4.w = f2bf(wv.w);
      *(us4*)((char*)As + swz(row, lc * 8)) = a4;
      *(us4*)((char*)Bs + swz(row, lc * 8)) = w4;
    }
    __syncthreads();

#pragma unroll
    for (int kk = 0; kk < 2; ++kk) {
      short8 af[4], bfr[4];
#pragma unroll
      for (int mi = 0; mi < 4; ++mi)
        af[mi] = *(const short8*)((const char*)As + swz(arow + mi * 16, kk * 64 + kcb));
#pragma unroll
      for (int ni = 0; ni < 4; ++ni)
        bfr[ni] = *(const short8*)((const char*)Bs + swz(brow + ni * 16, kk * 64 + kcb));
#pragma unroll
      for (int mi = 0; mi < 4; ++mi)
#pragma unroll
        for (int ni = 0; ni < 4; ++ni)
          acc[mi][ni] = __builtin_amdgcn_mfma_f32_16x16x32_bf16(af[mi], bfr[ni], acc[mi][ni], 0, 0, 0);
    }
  }

  const int rq = lane >> 4;
#pragma unroll
  for (int ni = 0; ni < 4; ++ni) {
    int col = n0 + wc * 64 + ni * 16 + frow;
    float bv = bias[col];
#pragma unroll
    for (int mi = 0; mi < 4; ++mi) {
#pragma unroll
      for (int r = 0; r < 4; ++r) {
        int grow = m0 + wr * 64 + mi * 16 + rq * 4 + r;
        if (grow < NNODE)
          Hb[(size_t)grow * D_H + col] = f2bf(fmaxf(acc[mi][ni][r] + bv, 0.f));
      }
    }
  }
}

// ---------------- Fallback B: fused gathered GEMM (round-1) ----------------
__global__ __launch_bounds__(256, 4)
void pool_aggr_gemm(const int* __restrict__ nidx_g,
                    const float* __restrict__ feat,
                    const float* __restrict__ Wm,
                    const float* __restrict__ bias,
                    float* __restrict__ out) {
  const int tid  = threadIdx.x;
  const int lane = tid & 63;
  const int wid  = tid >> 6;
  const int wr   = wid >> 1;
  const int wc   = wid & 1;
  const int n0   = blockIdx.x * BN;
  const int mb   = blockIdx.y;

  __shared__ __align__(16) unsigned short As[BM * BK];
  __shared__ __align__(16) unsigned short Bs[BM * BK];
  __shared__ int nid[BM];

  if (tid < BM) nid[tid] = nidx_g[mb * BM + tid];
  __syncthreads();

  const int lr = tid >> 4;
  const int lc = tid & 15;

  const float* aptr[8];
  const float* wptr[8];
#pragma unroll
  for (int p = 0; p < 8; ++p) {
    int row = p * 16 + lr;
    aptr[p] = feat + (size_t)nid[row] * D_IN + lc * 4;
    wptr[p] = Wm + (size_t)(n0 + row) * D_IN + lc * 4;
  }

  f32x4 acc[4][4];
#pragma unroll
  for (int i = 0; i < 4; ++i)
#pragma unroll
    for (int j = 0; j < 4; ++j)
      acc[i][j] = (f32x4){0.f, 0.f, 0.f, 0.f};

  const int frow = lane & 15;
  const int kcb  = (lane >> 4) * 16;
  const int arow = wr * 64 + frow;
  const int brow = wc * 64 + frow;

  for (int k0 = 0; k0 < D_IN; k0 += BK) {
    __syncthreads();
#pragma unroll
    for (int p = 0; p < 8; ++p) {
      int row = p * 16 + lr;
      f32x4 av = *(const f32x4*)(aptr[p] + k0);
      f32x4 wv = *(const f32x4*)(wptr[p] + k0);
      us4 a4, w4;
      a4.x = f2bf(av.x); a4.y = f2bf(av.y); a4.z = f2bf(av.z); a4.w = f2bf(av.w);
      w4.x = f2bf(wv.x); w4.y = f2bf(wv.y); w4.z = f2bf(wv.z); w4.w = f2bf(wv.w);
      *(us4*)((char*)As + swz(row, lc * 8)) = a4;
      *(us4*)((char*)Bs + swz(row, lc * 8)) = w4;
    }
    __syncthreads();

#pragma unroll
    for (int kk = 0; kk < 2; ++kk) {
      short8 af[4], bfr[4];
#pragma unroll
      for (int mi = 0; mi < 4; ++mi)
        af[mi] = *(const short8*)((const char*)As + swz(arow + mi * 16, kk * 64 + kcb));
#pragma unroll
      for (int ni = 0; ni < 4; ++ni)
        bfr[ni] = *(const short8*)((const char*)Bs + swz(brow + ni * 16, kk * 64 + kcb));
#pragma unroll
      for (int mi = 0; mi < 4; ++mi)
#pragma unroll
        for (int ni = 0; ni < 4; ++ni)
          acc[mi][ni] = __builtin_amdgcn_mfma_f32_16x16x32_bf16(af[mi], bfr[ni], acc[mi][ni], 0, 0, 0);
    }
  }

  const int rq = lane >> 4;
#pragma unroll
  for (int ni = 0; ni < 4; ++ni) {
    int col = n0 + wc * 64 + ni * 16 + frow;
    float bv = bias[col];
#pragma unroll
    for (int bl = 0; bl < 2; ++bl) {
      float s = 0.f;
#pragma unroll
      for (int m2 = 0; m2 < 2; ++m2) {
        int mi = bl * 2 + m2;
#pragma unroll
        for (int r = 0; r < 4; ++r)
          s += fmaxf(acc[mi][ni][r] + bv, 0.f);
      }
      s += __shfl_xor(s, 16);
      s += __shfl_xor(s, 32);
      if (rq == 0) {
        int bb = mb * 4 + wr * 2 + bl;
        out[(size_t)bb * D_H + col] = s * (1.0f / (float)S_NB);
      }
    }
  }
}

extern "C" void kernel_launch(void* const* d_in, const int* in_sizes, int n_in,
                              void* d_out, int out_size, void* d_ws, size_t ws_size,
                              hipStream_t stream) {
  const int*   nidx = (const int*)d_in[0];    // [10000,32]
  const float* feat = (const float*)d_in[1];  // [100000,512]
  const float* Wm   = (const float*)d_in[2];  // [512,512]
  const float* bias = (const float*)d_in[3];  // [512]
  float* out = (float*)d_out;                 // [10000,512]

  const size_t wb_elems = (size_t)D_H * D_IN;                        // 262144
  const size_t wb_bytes = wb_elems * sizeof(unsigned short);         // 0.5 MB
  const size_t h_bytes  = (size_t)NNODE * D_H * sizeof(unsigned short); // 102.4 MB

  if (ws_size >= wb_bytes + h_bytes) {
    unsigned short* Wb = (unsigned short*)d_ws;
    unsigned short* Hb = Wb + wb_elems;
    cvt_bf16<<<128, 256, 0, stream>>>(Wm, Wb, D_H * D_IN / 8);
    gemm_hf<<<NTILES, 256, 0, stream>>>(feat, Wb, bias, Hb);
    pool_mean4<<<NBATCH / 4, 256, 0, stream>>>(Hb, nidx, out);
  } else if (ws_size >= h_bytes) {
    unsigned short* Hb = (unsigned short*)d_ws;
    dim3 g1(D_H / BN, (NNODE + BM - 1) / BM);
    gemm_h<<<g1, 256, 0, stream>>>(feat, Wm, bias, Hb);
    pool_mean4<<<NBATCH / 4, 256, 0, stream>>>(Hb, nidx, out);
  } else {
    dim3 grid(D_H / BN, NBATCH / 4);
    pool_aggr_gemm<<<grid, 256, 0, stream>>>(nidx, feat, Wm, bias, out);
  }
}